// Round 8
// baseline (634.679 us; speedup 1.0000x reference)
//
#include <hip/hip_runtime.h>
#include <math.h>

#define BB 4
#define TT 4
#define CC 256
#define HH 30
#define WW 40
#define HWS (HH*WW)          // 1200
#define CHW (CC*HWS)         // 307200
#define NCG 32               // ci-groups of 8
#define PXS (NCG*HWS*8)      // f16 elements per blocked image [32][1200][8]
#define PLANE 2016           // LDS elems per cig plane: 252 px * 8

typedef __attribute__((ext_vector_type(8))) _Float16 half8;
typedef __attribute__((ext_vector_type(4))) float f32x4;
typedef __attribute__((ext_vector_type(16))) float f32x16;

// ---------------------------------------------------------------------------
// Pack x (all B,T) to f16 blocked pixel-major: x16[b][t][cig][p][8]
// ---------------------------------------------------------------------------
__global__ void pack_x16(const float* __restrict__ x, _Float16* __restrict__ x16) {
    int id = blockIdx.x * 256 + threadIdx.x;
    if (id >= BB * TT * NCG * HWS) return;
    int p = id % HWS;
    int cig = (id / HWS) % NCG;
    int bt = id / (HWS * NCG);
    const float* src = x + ((size_t)bt * CC + cig * 8) * HWS + p;
    half8 hv;
#pragma unroll
    for (int j = 0; j < 8; ++j) hv[j] = (_Float16)src[(size_t)j * HWS];
    *(half8*)&x16[(size_t)id * 8] = hv;
}

// ---------------------------------------------------------------------------
// h0 = sum_t x; c0 = h0.  c stays f32 [B][C][HW]; h emitted f16 blocked.
// ---------------------------------------------------------------------------
__global__ void init_hc(const float* __restrict__ x, _Float16* __restrict__ h16,
                        float* __restrict__ c) {
    int id = blockIdx.x * 256 + threadIdx.x;
    if (id >= BB * NCG * HWS) return;
    int p = id % HWS;
    int cig = (id / HWS) % NCG;
    int b = id / (HWS * NCG);
    float s[8];
#pragma unroll
    for (int j = 0; j < 8; ++j) s[j] = 0.f;
#pragma unroll
    for (int t = 0; t < TT; ++t) {
        const float* src = x + (((size_t)b * TT + t) * CC + cig * 8) * HWS + p;
#pragma unroll
        for (int j = 0; j < 8; ++j) s[j] += src[(size_t)j * HWS];
    }
    half8 hv;
    float* cp = c + ((size_t)b * CC + cig * 8) * HWS + p;
#pragma unroll
    for (int j = 0; j < 8; ++j) { cp[(size_t)j * HWS] = s[j]; hv[j] = (_Float16)s[j]; }
    *(half8*)&h16[(size_t)id * 8] = hv;
}

// ---------------------------------------------------------------------------
// xtilde16[b][cig][p][8] = (f16)(x_f32[b,t,ci,p] * a[b,p])
// ---------------------------------------------------------------------------
__global__ void xtilde_kernel(const float* __restrict__ xt, const float* __restrict__ a,
                              _Float16* __restrict__ xt16) {
    int id = blockIdx.x * 256 + threadIdx.x;
    if (id >= BB * NCG * HWS) return;
    int p = id % HWS;
    int cig = (id / HWS) % NCG;
    int b = id / (HWS * NCG);
    float sc = a[(size_t)b * HWS + p];
    const float* src = xt + ((size_t)b * TT * CC + cig * 8) * HWS + p;
    half8 hv;
#pragma unroll
    for (int j = 0; j < 8; ++j) hv[j] = (_Float16)(src[(size_t)j * HWS] * sc);
    *(half8*)&xt16[(size_t)id * 8] = hv;
}

// ---------------------------------------------------------------------------
// Pack weights to f16: layout [kg=k/8][Cout][k%8]
// ---------------------------------------------------------------------------
__global__ void pack_weights(const float* __restrict__ W1,
                             const float* __restrict__ W2,
                             _Float16* __restrict__ wt, int Cout) {
    int idx = blockIdx.x * 256 + threadIdx.x;
    if (idx >= 4608 * Cout) return;
    int k = idx / Cout;
    int n = idx - k * Cout;
    float v = (k < 2304) ? W1[(size_t)k * Cout + n]
                         : W2[(size_t)(k - 2304) * Cout + n];
    wt[((size_t)(k >> 3) * Cout + n) * 8 + (k & 7)] = (_Float16)v;
}

// ---------------------------------------------------------------------------
// MFMA dual 3x3 conv — 32x32x16 edition.
// Rationale: R0-R7 pinned at ~51us across every resource change; the one
// invariant was instruction granularity (16x16x32). 32x32x16 halves MFMA
// instruction count at a 15% faster pipe, and the 160px x 64co wave tile
// halves per-CU LDS read demand -> MFMA becomes the binding pipe (~25us).
// Layouts (derived from the verified doubled-K pattern of our working
// 16x16x32 kernel): A lane l: row=l&31, k=8*(l>>5)+j (j=0..7 contiguous ci
// -> one b128 from the [8ci]-blocked LDS); B lane l: col=l&31, same k;
// C/D [m74/m101]: col=lane&31, row=(reg&3)+8*(reg>>2)+4*(lane>>5).
// Block: 1 batch x 4 image rows = 160px (5 M-frags of 32) x 256 couts
// (4 waves x NW=2 x 32). 8 slices x 32 M-units = 256 blocks, XCD-homed.
// Row-tile 7 (rows 28-29) is partial: computed fully against zero-padded
// LDS rows, store-masked at px>=1200.
// Plain __syncthreads (KBAR's 31.5ms outlier in R7 = intermittent hazard);
// stage loads issued POST-barrier so they overlap all 9 taps of compute.
// ---------------------------------------------------------------------------
template<int NW, int NZ, int NY, int ZT>
__global__ __launch_bounds__(256, 1) void conv_mfma(
    const _Float16* __restrict__ in0, long bs0,
    const _Float16* __restrict__ in1, long bs1,
    const _Float16* __restrict__ wt,
    const float* __restrict__ b1, const float* __restrict__ b2,
    float* __restrict__ out, int Cout)
{
    constexpr int NK = 8 / NZ;                      // K-iters (32 ci each)
    constexpr int SLICES = NY * ZT;                 // must be 8
    constexpr int PERX = SLICES / 8;
    constexpr int MU = 32;                          // 4 batches x 8 row-tiles
    __shared__ alignas(16) _Float16 s_a[2][4 * PLANE];

    const int tid = threadIdx.x;
    const int l = tid & 63, wv = tid >> 6;
    const int half = l >> 5;                        // lane half (k-block)
    const int lane_co = l & 31;                     // N index within frag

    // ---- XCD-homed decode (8*PERX*MU = 256 blocks) ----
    const int lin = blockIdx.x;
    const int xcd = lin & 7;
    const int idx = lin >> 3;                       // 0..31
    const int sl = xcd * PERX + idx / MU;
    const int mu = idx % MU;
    const int zz = sl / NY;
    const int yy = sl - zz * NY;

    const int b = mu >> 3;                          // batch
    const int rt = mu & 7;                          // row-tile (4 rows)
    const int pix0 = rt * 160;
    const int y0 = rt * 4;
    const int n0 = yy * (4 * NW * 32) + wv * (NW * 32);
    const int src = zz / NZ;
    const int ci_start = (zz % NZ) * (CC / NZ);
    const int kgb0 = src * 288 + (ci_start >> 3);

    const _Float16* inp = (src ? (in1 + (size_t)b * bs1) : (in0 + (size_t)b * bs0))
                          + (size_t)(ci_start >> 3) * HWS * 8;

    // ---- staging geometry: 4 cig x 6 rows x 42 = 1008 items, 4/thread ----
    bool iv[4], pv[4];
    const _Float16* pj[4];
    int ldsoff[4];
#pragma unroll
    for (int j = 0; j < 4; ++j) {
        int item = tid + j * 256;
        iv[j] = item < 1008;
        int it = iv[j] ? item : 0;
        int cig = it / 252;
        int pix = it - cig * 252;
        int row = pix / 42;
        int px = pix - row * 42;
        int xx = px - 1, yy2 = y0 + row - 1;
        pv[j] = iv[j] && xx >= 0 && xx < WW && yy2 >= 0 && yy2 < HH;
        pj[j] = inp + ((size_t)cig * HWS + yy2 * WW + xx) * 8;
        ldsoff[j] = cig * PLANE + pix * 8;
    }

    // ---- accumulators: 5 M-frags x NW, 16 f32 each ----
    f32x16 acc[5][NW];
#pragma unroll
    for (int nt = 0; nt < NW; ++nt) {
        int co = n0 + nt * 32 + lane_co;
        float bias = (zz == 0) ? (b1[co] + b2[co]) : 0.f;
#pragma unroll
        for (int f = 0; f < 5; ++f)
#pragma unroll
            for (int rg = 0; rg < 16; ++rg) acc[f][nt][rg] = bias;
    }

    // ---- per-frag LDS pixel base (row-in-tile decode, per lane) ----
    int hb[5];
#pragma unroll
    for (int f = 0; f < 5; ++f) {
        int p = f * 32 + lane_co;
        int ry = p / 40;
        int rx = p - ry * 40;
        hb[f] = ry * 42 + rx;
    }

    // ---- staging: pure b128 copy ----
    half8 sr[4];
    auto stage_issue = [&](int kk) {
#pragma unroll
        for (int j = 0; j < 4; ++j) if (pv[j])
            sr[j] = *(const half8*)(pj[j] + (size_t)kk * (4 * HWS * 8));
    };
    auto stage_write = [&](int kk) {
#pragma unroll
        for (int j = 0; j < 4; ++j) if (iv[j]) {
            half8 hv = {0, 0, 0, 0, 0, 0, 0, 0};
            if (pv[j]) hv = sr[j];
            *(half8*)&s_a[kk & 1][ldsoff[j]] = hv;
        }
    };

    const half8* wp = (const half8*)wt;
    half8 wA[2][NW], wB[2][NW];

#define WLOADX(S, TAP) do {                                                \
    _Pragma("unroll")                                                      \
    for (int ks = 0; ks < 2; ++ks)                                         \
    _Pragma("unroll")                                                      \
    for (int nt = 0; nt < NW; ++nt)                                        \
        S[ks][nt] = wp[(size_t)(kgb0 + k * 4 + (TAP) * 32 + ks * 2 + half) \
                       * Cout + n0 + nt * 32 + lane_co];                   \
} while (0)

#define CTAPX(S, TAP) do {                                                 \
    constexpr int dy_ = (TAP) / 3, dx_ = (TAP) % 3;                        \
    _Pragma("unroll")                                                      \
    for (int f = 0; f < 5; ++f)                                            \
    _Pragma("unroll")                                                      \
    for (int ks = 0; ks < 2; ++ks) {                                       \
        half8 af = *(const half8*)&s_a[k & 1]                              \
            [(ks * 2 + half) * PLANE + (hb[f] + dy_ * 42 + dx_) * 8];      \
        _Pragma("unroll")                                                  \
        for (int nt = 0; nt < NW; ++nt)                                    \
            acc[f][nt] = __builtin_amdgcn_mfma_f32_32x32x16_f16(           \
                af, S[ks][nt], acc[f][nt], 0, 0, 0);                       \
    }                                                                      \
} while (0)

    // prologue: stage tile 0
    stage_issue(0);
    stage_write(0);

#pragma unroll
    for (int k = 0; k < NK; ++k) {
        WLOADX(wA, 0);                   // tap0 weights return during barrier wait
        __syncthreads();                 // s_a[k&1] ready (full drain, stable)
        __builtin_amdgcn_s_setprio(1);
        if (k + 1 < NK) stage_issue(k + 1);  // 4 loads fly over all 9 taps
        WLOADX(wB, 1); CTAPX(wA, 0);
        WLOADX(wA, 2); CTAPX(wB, 1);
        WLOADX(wB, 3); CTAPX(wA, 2);
        WLOADX(wA, 4); CTAPX(wB, 3);
        WLOADX(wB, 5); CTAPX(wA, 4);
        WLOADX(wA, 6); CTAPX(wB, 5);
        WLOADX(wB, 7); CTAPX(wA, 6);
        WLOADX(wA, 8); CTAPX(wB, 7);
        CTAPX(wA, 8);
        __builtin_amdgcn_s_setprio(0);
        if (k + 1 < NK) stage_write(k + 1);  // waits only on the 4 stage loads
    }
#undef WLOADX
#undef CTAPX

    // ---- store: C/D row = (reg&3)+8*(reg>>2)+4*half, col = lane_co ----
    out += (size_t)zz * BB * Cout * HWS;
#pragma unroll
    for (int f = 0; f < 5; ++f) {
#pragma unroll
        for (int nt = 0; nt < NW; ++nt) {
            int co = n0 + nt * 32 + lane_co;
            float* op = out + ((size_t)b * Cout + co) * HWS;
#pragma unroll
            for (int rg = 0; rg < 4; ++rg) {
                int px = pix0 + f * 32 + 8 * rg + 4 * half;
                if (px < HWS) {
                    f32x4 v = {acc[f][nt][4 * rg], acc[f][nt][4 * rg + 1],
                               acc[f][nt][4 * rg + 2], acc[f][nt][4 * rg + 3]};
                    *(f32x4*)&op[px] = v;
                }
            }
        }
    }
}

// ---------------------------------------------------------------------------
// att = tanh(sum of 8 stacked K-split partials)  (float4 loads)
// ---------------------------------------------------------------------------
__global__ void add_tanh8(const float* __restrict__ a0,
                          float* __restrict__ o, int n4) {
    int id = blockIdx.x * 256 + threadIdx.x;
    if (id >= n4) return;
    const f32x4* av = (const f32x4*)a0;
    f32x4 s = {0.f, 0.f, 0.f, 0.f};
#pragma unroll
    for (int z = 0; z < 8; ++z) s += av[id + (size_t)z * n4];
    f32x4 rr;
#pragma unroll
    for (int j = 0; j < 4; ++j) rr[j] = tanhf(s[j]);
    ((f32x4*)o)[id] = rr;
}

// ---------------------------------------------------------------------------
// K-split attention score: part[b][ch][p] = sum_{ca in chunk} sum_tap
//   att[b,ca,y+dy-1,x+dx-1] * Va[tap,ca]
// ---------------------------------------------------------------------------
__global__ __launch_bounds__(256) void att_e_part(
    const float* __restrict__ att, const float* __restrict__ Va,
    float* __restrict__ part)
{
    __shared__ float red[4][64];
    const int lane = threadIdx.x & 63, wv = threadIdx.x >> 6;
    const int p = blockIdx.x * 64 + lane;
    const int b = blockIdx.y, ch = blockIdx.z;
    const bool valid = (p < HWS);
    const int pc = valid ? p : 0;
    const int y = pc / WW, x = pc - (pc / WW) * WW;

    float acc = 0.f;
    if (valid) {
        const int ca0 = ch * 32 + wv * 8;
#pragma unroll
        for (int j = 0; j < 8; ++j) {
            const int ca = ca0 + j;
            const float* base = att + ((size_t)b * CC + ca) * HWS;
            const float* va = Va + ca;
#pragma unroll
            for (int dy = 0; dy < 3; ++dy) {
                int yy = y + dy - 1;
                if (yy < 0 || yy >= HH) continue;
#pragma unroll
                for (int dx = 0; dx < 3; ++dx) {
                    int xx = x + dx - 1;
                    if (xx < 0 || xx >= WW) continue;
                    acc = fmaf(base[yy * WW + xx], va[(dy * 3 + dx) * CC], acc);
                }
            }
        }
    }
    red[wv][lane] = acc;
    __syncthreads();
    if (wv == 0 && valid)
        part[((size_t)b * 8 + ch) * HWS + p] =
            red[0][lane] + red[1][lane] + red[2][lane] + red[3][lane];
}

// ---------------------------------------------------------------------------
// softmax over HW per batch, summing the 8 K-split partials first (in LDS)
// ---------------------------------------------------------------------------
__global__ __launch_bounds__(256) void softmax_kernel(
    const float* __restrict__ part, float* __restrict__ a)
{
    __shared__ float se[HWS];
    __shared__ float red[256];
    int b = blockIdx.x;
    int tid = threadIdx.x;

    for (int i = tid; i < HWS; i += 256) {
        float s = 0.f;
#pragma unroll
        for (int ch = 0; ch < 8; ++ch)
            s += part[((size_t)b * 8 + ch) * HWS + i];
        se[i] = s;
    }
    __syncthreads();

    float m = -1e30f;
    for (int i = tid; i < HWS; i += 256) m = fmaxf(m, se[i]);
    red[tid] = m;
    __syncthreads();
    for (int s = 128; s > 0; s >>= 1) {
        if (tid < s) red[tid] = fmaxf(red[tid], red[tid + s]);
        __syncthreads();
    }
    m = red[0];
    __syncthreads();

    float sum = 0.f;
    for (int i = tid; i < HWS; i += 256) {
        float v = expf(se[i] - m);
        se[i] = v;
        sum += v;
    }
    red[tid] = sum;
    __syncthreads();
    for (int s = 128; s > 0; s >>= 1) {
        if (tid < s) red[tid] += red[tid + s];
        __syncthreads();
    }
    float inv = 1.f / red[0];
    for (int i = tid; i < HWS; i += 256)
        a[(size_t)b * HWS + i] = se[i] * inv;
}

// ---------------------------------------------------------------------------
// LSTM gate update; emits h16 (blocked f16) always, h f32 only on last step.
// ---------------------------------------------------------------------------
__global__ void gate_update(const float* __restrict__ g0, const float* __restrict__ g1,
                            float* __restrict__ c, _Float16* __restrict__ h16,
                            float* __restrict__ h32) {
    int id = blockIdx.x * 256 + threadIdx.x;
    if (id >= BB * NCG * HWS) return;
    int p = id % HWS;
    int cig = (id / HWS) % NCG;
    int b = id / (HWS * NCG);
    const int ci0 = cig * 8;
    half8 hv;
#pragma unroll
    for (int j = 0; j < 8; ++j) {
        size_t base = ((size_t)b * 4 * CC + ci0 + j) * HWS + p;
        float gi = g0[base] + g1[base];
        float gf = g0[base + (size_t)CHW] + g1[base + (size_t)CHW];
        float gc = g0[base + 2 * (size_t)CHW] + g1[base + 2 * (size_t)CHW];
        float go = g0[base + 3 * (size_t)CHW] + g1[base + 3 * (size_t)CHW];
        float i_ = 1.f / (1.f + expf(-gi));
        float f_ = 1.f / (1.f + expf(-gf));
        float o_ = 1.f / (1.f + expf(-go));
        size_t cix = ((size_t)b * CC + ci0 + j) * HWS + p;
        float cn = f_ * c[cix] + i_ * tanhf(gc);
        c[cix] = cn;
        float hn = o_ * tanhf(cn);
        hv[j] = (_Float16)hn;
        if (h32) h32[cix] = hn;
    }
    *(half8*)&h16[(size_t)id * 8] = hv;
}

// ---------------------------------------------------------------------------
extern "C" void kernel_launch(void* const* d_in, const int* in_sizes, int n_in,
                              void* d_out, int out_size, void* d_ws, size_t ws_size,
                              hipStream_t stream) {
    const float* x   = (const float*)d_in[0];
    const float* Wa  = (const float*)d_in[1];
    const float* ba  = (const float*)d_in[2];
    const float* Ua  = (const float*)d_in[3];
    const float* bua = (const float*)d_in[4];
    const float* Va  = (const float*)d_in[5];
    const float* Wx  = (const float*)d_in[6];
    const float* bx  = (const float*)d_in[7];
    const float* Uh  = (const float*)d_in[8];
    const float* bh  = (const float*)d_in[9];
    float* out = (float*)d_out;

    char* wsb = (char*)d_ws;
    const size_t NCHW = (size_t)BB * CHW;
    _Float16* wtg  = (_Float16*)wsb;              wsb += (size_t)4608 * 1024 * 2;
    _Float16* wta  = (_Float16*)wsb;              wsb += (size_t)4608 * 256 * 2;
    _Float16* x16  = (_Float16*)wsb;              wsb += (size_t)BB * TT * PXS * 2;
    _Float16* h16  = (_Float16*)wsb;              wsb += (size_t)BB * PXS * 2;
    _Float16* xt16 = (_Float16*)wsb;              wsb += (size_t)BB * PXS * 2;
    float* cb   = (float*)wsb;                    wsb += NCHW * 4;
    float* g01  = (float*)wsb;                    wsb += 8 * NCHW * 4;   // z-stacked
    float* att  = (float*)wsb;                    wsb += NCHW * 4;
    float* part = (float*)wsb;                    wsb += (size_t)BB * 8 * HWS * 4;
    float* a    = (float*)wsb;
    // att01 (8 z-stacked partials, Cout=256) aliases g01 (disjoint lifetime)
    float* att01 = g01;

    pack_weights<<<dim3((4608 * 1024 + 255) / 256), dim3(256), 0, stream>>>(
        Wx, Uh, wtg, 1024);
    pack_weights<<<dim3((4608 * 256 + 255) / 256), dim3(256), 0, stream>>>(
        Wa, Ua, wta, 256);
    pack_x16<<<dim3((BB * TT * NCG * HWS + 255) / 256), dim3(256), 0, stream>>>(
        x, x16);

    const int nblk = BB * NCG * HWS;              // 153600
    init_hc<<<dim3((nblk + 255) / 256), dim3(256), 0, stream>>>(x, h16, cb);

    const int n4 = (int)(NCHW / 4);

    for (int t = 0; t < TT; ++t) {
        // attention partials: 32x32 MFMA, NW=2 (256 couts/block), NZ=4
        // ci-chunks x 2 src = 8 slices x 32 M-units = 256 blocks (NK=2).
        conv_mfma<2, 4, 1, 8><<<dim3(256), dim3(256), 0, stream>>>(
            h16, (long)PXS, x16 + (size_t)t * PXS, (long)TT * PXS,
            wta, ba, bua, att01, 256);
        add_tanh8<<<dim3((n4 + 255) / 256), dim3(256), 0, stream>>>(
            att01, att, n4);

        att_e_part<<<dim3(19, BB, 8), dim3(256), 0, stream>>>(att, Va, part);
        softmax_kernel<<<dim3(BB), dim3(256), 0, stream>>>(part, a);

        // x_tilde in f16 blocked
        xtilde_kernel<<<dim3((nblk + 255) / 256), dim3(256), 0, stream>>>(
            x + (size_t)t * CHW, a, xt16);

        // gates: 32x32 MFMA, NW=2, NY=4 cout-chunks x 2 src = 8 slices
        // x 32 M-units = 256 blocks (NK=8).
        conv_mfma<2, 1, 4, 2><<<dim3(256), dim3(256), 0, stream>>>(
            xt16, (long)PXS, h16, (long)PXS, wtg, bx, bh, g01, 1024);

        gate_update<<<dim3((nblk + 255) / 256), dim3(256), 0, stream>>>(
            g01, g01 + 4 * NCHW, cb, h16, (t == TT - 1) ? out : nullptr);
    }
}